// Round 9
// baseline (327.947 us; speedup 1.0000x reference)
//
#include <hip/hip_runtime.h>

#define NN 384
#define RR 8
#define NR (NN * RR)   // 3072
#define BB 64          // (j,k) pairs per block

typedef _Float16 half2v __attribute__((ext_vector_type(2)));
typedef _Float16 half8v __attribute__((ext_vector_type(8)));

struct h2x4 { half2v v[4]; };
static __device__ inline h2x4 split4(half8v h) { return __builtin_bit_cast(h2x4, h); }
static __device__ inline half2v rl(int v, int l) {
    return __builtin_bit_cast(half2v, __builtin_amdgcn_readlane(v, l));
}

// out[b,i] = sum_{a,b2,c} A[a,i,b2]*Bf[b2,j_b,c]*C[c,k_b,a]
// G[b2,a] = sum_c Bf[b2,j,c]*C[c,k,a];  out[b,i] = sum_p A2[i,p]*G[p], p=a*8+b2.
// Round-9 change: the wave's 8 G-rows (1KB) are loaded with ONE cooperative
// ds_read_b128 and redistributed via v_readlane -> SGPR operand of fdot2,
// eliminating the 64 broadcast ds_reads/wave (57% of LDS-pipe time in r8).
__global__ __launch_bounds__(512, 4)
void dtn_dot2c(const float* __restrict__ A, const float* __restrict__ Bf,
               const float* __restrict__ C, const int* __restrict__ x,
               float* __restrict__ out)
{
    // A2c[c][i]: 16B chunk = f16 of A2[i][8c..8c+7]
    __shared__ __align__(16) _Float16 A2c[8 * NN * 8];   // 49152 B
    __shared__ __align__(16) _Float16 Gh[BB * 64];       // 8192 B

    const int t = threadIdx.x;
    const long b0 = (long)blockIdx.x * BB;

    // ---- Stage A2c[(a*NN+i)*8 + e] = f16(A[a*NR + i*8 + e]); 3072 chunks, 6 iters.
    #pragma unroll
    for (int it = 0; it < 6; ++it) {
        const int idx = t + it * 512;     // 0..3071
        const int i = idx >> 3;
        const int a = idx & 7;
        const float4* src = reinterpret_cast<const float4*>(A + (size_t)a * NR + (size_t)i * RR);
        const float4 f0 = src[0];
        const float4 f1 = src[1];
        half8v h;
        h[0] = (_Float16)f0.x; h[1] = (_Float16)f0.y; h[2] = (_Float16)f0.z; h[3] = (_Float16)f0.w;
        h[4] = (_Float16)f1.x; h[5] = (_Float16)f1.y; h[6] = (_Float16)f1.z; h[7] = (_Float16)f1.w;
        *reinterpret_cast<half8v*>(&A2c[(size_t)(a * NN + i) * 8]) = h;
    }

    // ---- G: thread -> (pair bl = t>>3, column a = t&7); computes G[b2][a], b2=0..7.
    {
        const int bl = t >> 3;
        const int a  = t & 7;
        const int j = x[2 * (b0 + bl)];
        const int k = x[2 * (b0 + bl) + 1];
        const float* Bj = Bf + (size_t)j * RR;           // Bf[b2,j,c] at Bj[b2*NR + c]
        const float* Ck = C + (size_t)k * RR + a;        // C[c,k,a]   at Ck[c*NR]
        float ck[8];
        #pragma unroll
        for (int c = 0; c < 8; ++c)
            ck[c] = Ck[(size_t)c * NR];
        half8v h;
        #pragma unroll
        for (int b2 = 0; b2 < 8; ++b2) {
            const float4* br = reinterpret_cast<const float4*>(Bj + (size_t)b2 * NR);
            const float4 r0 = br[0];
            const float4 r1 = br[1];
            const float s = r0.x * ck[0] + r0.y * ck[1] + r0.z * ck[2] + r0.w * ck[3]
                          + r1.x * ck[4] + r1.y * ck[5] + r1.z * ck[6] + r1.w * ck[7];
            h[b2] = (_Float16)s;
        }
        *reinterpret_cast<half8v*>(&Gh[bl * 64 + a * 8]) = h;   // p = a*8 + b2
    }

    __syncthreads();

    // ---- Epilogue: lane = t&63 (i-group), wave wv = t>>6 owns pairs wv*8..wv*8+7.
    const int lane = t & 63;
    const int wv = t >> 6;

    // Cooperative G load: lane holds chunk (pp = lane>>3, c = lane&7) of this
    // wave's 8 pairs -- one ds_read_b128 covers the wave's whole 1KB G set.
    const int4 greg = *reinterpret_cast<const int4*>(
        &Gh[(wv * 8 + (lane >> 3)) * 64 + (lane & 7) * 8]);

    float acc[8][6];
    #pragma unroll
    for (int pp = 0; pp < 8; ++pp)
        #pragma unroll
        for (int ii = 0; ii < 6; ++ii)
            acc[pp][ii] = 0.f;

    #pragma unroll 1
    for (int c = 0; c < 8; ++c) {
        h2x4 av[6];
        #pragma unroll
        for (int ii = 0; ii < 6; ++ii)
            av[ii] = split4(*reinterpret_cast<const half8v*>(
                &A2c[(size_t)(c * NN + lane + 64 * ii) * 8]));
        #pragma unroll
        for (int pp = 0; pp < 8; ++pp) {
            const int sl = pp * 8 + c;            // source lane holding chunk (pp, c)
            const half2v g0 = rl(greg.x, sl);
            const half2v g1 = rl(greg.y, sl);
            const half2v g2 = rl(greg.z, sl);
            const half2v g3 = rl(greg.w, sl);
            #pragma unroll
            for (int ii = 0; ii < 6; ++ii) {
                float s = acc[pp][ii];
                s = __builtin_amdgcn_fdot2(g0, av[ii].v[0], s, false);
                s = __builtin_amdgcn_fdot2(g1, av[ii].v[1], s, false);
                s = __builtin_amdgcn_fdot2(g2, av[ii].v[2], s, false);
                s = __builtin_amdgcn_fdot2(g3, av[ii].v[3], s, false);
                acc[pp][ii] = s;
            }
        }
    }

    // ---- Store: per (pp,ii) the wave's 64 lanes write 256B contiguous.
    float* obase = out + (size_t)(b0 + wv * 8) * NN + lane;
    #pragma unroll
    for (int pp = 0; pp < 8; ++pp) {
        #pragma unroll
        for (int ii = 0; ii < 6; ++ii)
            obase[(size_t)pp * NN + ii * 64] = acc[pp][ii];
    }
}

extern "C" void kernel_launch(void* const* d_in, const int* in_sizes, int n_in,
                              void* d_out, int out_size, void* d_ws, size_t ws_size,
                              hipStream_t stream) {
    const float* A  = (const float*)d_in[0];
    const float* Bf = (const float*)d_in[1];
    const float* C  = (const float*)d_in[2];
    const int*   x  = (const int*)d_in[3];
    float* out = (float*)d_out;
    const int B = in_sizes[3] / 2;           // 524288
    dtn_dot2c<<<B / BB, 512, 0, stream>>>(A, Bf, C, x, out);
}

// Round 10
// 266.386 us; speedup vs baseline: 1.2311x; 1.2311x over previous
//
#include <hip/hip_runtime.h>

#define NN 384
#define RR 8
#define NR (NN * RR)   // 3072
#define BATCH 64       // pairs per batch (epilogue granularity, = r8's BB)
#define NBATCH 4
#define BB (BATCH * NBATCH)   // 256 pairs per block

typedef _Float16 half2v __attribute__((ext_vector_type(2)));
typedef _Float16 half8v __attribute__((ext_vector_type(8)));

struct h2x4 { half2v v[4]; };
static __device__ inline h2x4 split4(half8v h) { return __builtin_bit_cast(h2x4, h); }

// out[b,i] = sum_{a,b2,c} A[a,i,b2]*Bf[b2,j_b,c]*C[c,k_b,a]
// G[b2,a] = sum_c Bf[b2,j,c]*C[c,k,a];  out[b,i] = sum_p A2[i,p]*G[p], p=a*8+b2.
// r10: r8's proven epilogue x 4 batches per block -- A2 staging amortized 4x,
// store bursts of batch n overlap compute of batch n+1. LDS 80KB -> 2 blocks/CU.
__global__ __launch_bounds__(512, 4)
void dtn_dot2d(const float* __restrict__ A, const float* __restrict__ Bf,
               const float* __restrict__ C, const int* __restrict__ x,
               float* __restrict__ out)
{
    // A2c[c][i]: 16B chunk = f16 of A2[i][8c..8c+7]
    __shared__ __align__(16) _Float16 A2c[8 * NN * 8];   // 49152 B
    __shared__ __align__(16) _Float16 Gh[BB * 64];       // 32768 B

    const int t = threadIdx.x;
    const long b0 = (long)blockIdx.x * BB;

    // ---- Stage A2c[(a*NN+i)*8 + e] = f16(A[a*NR + i*8 + e]); 3072 chunks, 6 iters.
    #pragma unroll
    for (int it = 0; it < 6; ++it) {
        const int idx = t + it * 512;     // 0..3071
        const int i = idx >> 3;
        const int a = idx & 7;
        const float4* src = reinterpret_cast<const float4*>(A + (size_t)a * NR + (size_t)i * RR);
        const float4 f0 = src[0];
        const float4 f1 = src[1];
        half8v h;
        h[0] = (_Float16)f0.x; h[1] = (_Float16)f0.y; h[2] = (_Float16)f0.z; h[3] = (_Float16)f0.w;
        h[4] = (_Float16)f1.x; h[5] = (_Float16)f1.y; h[6] = (_Float16)f1.z; h[7] = (_Float16)f1.w;
        *reinterpret_cast<half8v*>(&A2c[(size_t)(a * NN + i) * 8]) = h;
    }

    // ---- G for all 4 batches: thread -> (pair bl, column a = t&7), 4 pairs/thread.
    #pragma unroll 1
    for (int bt = 0; bt < NBATCH; ++bt) {
        const int bl = bt * BATCH + (t >> 3);
        const int a  = t & 7;
        const int j = x[2 * (b0 + bl)];
        const int k = x[2 * (b0 + bl) + 1];
        const float* Bj = Bf + (size_t)j * RR;           // Bf[b2,j,c] at Bj[b2*NR + c]
        const float* Ck = C + (size_t)k * RR + a;        // C[c,k,a]   at Ck[c*NR]
        float ck[8];
        #pragma unroll
        for (int c = 0; c < 8; ++c)
            ck[c] = Ck[(size_t)c * NR];
        half8v h;
        #pragma unroll
        for (int b2 = 0; b2 < 8; ++b2) {
            const float4* br = reinterpret_cast<const float4*>(Bj + (size_t)b2 * NR);
            const float4 r0 = br[0];
            const float4 r1 = br[1];
            const float s = r0.x * ck[0] + r0.y * ck[1] + r0.z * ck[2] + r0.w * ck[3]
                          + r1.x * ck[4] + r1.y * ck[5] + r1.z * ck[6] + r1.w * ck[7];
            h[b2] = (_Float16)s;
        }
        *reinterpret_cast<half8v*>(&Gh[bl * 64 + a * 8]) = h;   // p = a*8 + b2
    }

    __syncthreads();

    // ---- Epilogue: 4 passes of r8's proven kernel. lane = i-group, wave wv owns
    // pairs (bt*64 + wv*8 .. +7); i = lane + 64*ii.
    const int lane = t & 63;
    const int wv = t >> 6;

    #pragma unroll 1
    for (int bt = 0; bt < NBATCH; ++bt) {
        float acc[8][6];
        #pragma unroll
        for (int pp = 0; pp < 8; ++pp)
            #pragma unroll
            for (int ii = 0; ii < 6; ++ii)
                acc[pp][ii] = 0.f;

        #pragma unroll 1
        for (int c = 0; c < 8; ++c) {
            h2x4 av[6];
            #pragma unroll
            for (int ii = 0; ii < 6; ++ii)
                av[ii] = split4(*reinterpret_cast<const half8v*>(
                    &A2c[(size_t)(c * NN + lane + 64 * ii) * 8]));
            #pragma unroll
            for (int pp = 0; pp < 8; ++pp) {
                const h2x4 g = split4(*reinterpret_cast<const half8v*>(
                    &Gh[(bt * BATCH + wv * 8 + pp) * 64 + c * 8]));
                #pragma unroll
                for (int ii = 0; ii < 6; ++ii) {
                    float s = acc[pp][ii];
                    s = __builtin_amdgcn_fdot2(g.v[0], av[ii].v[0], s, false);
                    s = __builtin_amdgcn_fdot2(g.v[1], av[ii].v[1], s, false);
                    s = __builtin_amdgcn_fdot2(g.v[2], av[ii].v[2], s, false);
                    s = __builtin_amdgcn_fdot2(g.v[3], av[ii].v[3], s, false);
                    acc[pp][ii] = s;
                }
            }
        }

        // Store: per (pp,ii) the wave's 64 lanes write 256B contiguous.
        float* obase = out + (size_t)(b0 + bt * BATCH + wv * 8) * NN + lane;
        #pragma unroll
        for (int pp = 0; pp < 8; ++pp) {
            #pragma unroll
            for (int ii = 0; ii < 6; ++ii)
                obase[(size_t)pp * NN + ii * 64] = acc[pp][ii];
        }
    }
}

extern "C" void kernel_launch(void* const* d_in, const int* in_sizes, int n_in,
                              void* d_out, int out_size, void* d_ws, size_t ws_size,
                              hipStream_t stream) {
    const float* A  = (const float*)d_in[0];
    const float* Bf = (const float*)d_in[1];
    const float* C  = (const float*)d_in[2];
    const int*   x  = (const int*)d_in[3];
    float* out = (float*)d_out;
    const int B = in_sizes[3] / 2;           // 524288
    dtn_dot2d<<<B / BB, 512, 0, stream>>>(A, Bf, C, x, out);
}